// Round 9
// baseline (245.049 us; speedup 1.0000x reference)
//
#include <hip/hip_runtime.h>

// ---------------------------------------------------------------------------
// MultiHeadAttention — fp32 in/out, bf16 compute.
// Round 9: flash v6 — r7 body (mask fast-path REVERTED: it regressed) +
// 2-tile ILP per iteration (two independent QK->exp->PV chains per wave).
// GEMMs: BK=64 (half the barrier drains), row-XOR seg swizzle.
// BS=2, QLEN=2048, DIM=1024, NH=16, DH=64.
// d_out (16 MB fp32): [ Q_bf16 8MB | X_bf16 8MB ]  (dead before O-GEMM writes)
// d_ws  (>=32MB):     [ K_bf16 8MB | C_bf16 8MB | Vt 8MB | W_bf16 8MB ]
// ---------------------------------------------------------------------------

#define BS    2
#define QLEN  2048
#define DIM   1024
#define NH    16
#define DH    64
#define MTOK  (BS * QLEN)          // 4096 token rows

// Q projection scale: (1/8) * log2(e) so attention uses exp2 directly.
#define QSCALE 0.18033688011112042f

typedef __attribute__((ext_vector_type(8))) short short8;   // 8 bf16
typedef __attribute__((ext_vector_type(4))) float float4_t; // MFMA acc
typedef __attribute__((ext_vector_type(4))) int   int4_t;

__device__ __forceinline__ ushort f2bf(float f) {   // RNE
    unsigned u = __float_as_uint(f);
    return (ushort)((u + 0x7fffu + ((u >> 16) & 1u)) >> 16);
}
__device__ __forceinline__ short8 pack8(float4 a0, float4 a1) {
    short8 r;
    r[0] = (short)f2bf(a0.x); r[1] = (short)f2bf(a0.y);
    r[2] = (short)f2bf(a0.z); r[3] = (short)f2bf(a0.w);
    r[4] = (short)f2bf(a1.x); r[5] = (short)f2bf(a1.y);
    r[6] = (short)f2bf(a1.z); r[7] = (short)f2bf(a1.w);
    return r;
}

// async global->LDS, 16 B per lane (lds dest = wave-uniform base + lane*16).
__device__ __forceinline__ void glds16(const void* g, void* l) {
    __builtin_amdgcn_global_load_lds(
        (const __attribute__((address_space(1))) unsigned int*)g,
        (__attribute__((address_space(3))) unsigned int*)l, 16, 0, 0);
}

// ---------------------------------------------------------------------------
// Combined fp32 -> bf16 convert: X (4M) + 4 weights (1M each), one launch.
// ---------------------------------------------------------------------------
__global__ __launch_bounds__(256) void conv_all(
    const float* __restrict__ x,  const float* __restrict__ qw,
    const float* __restrict__ kw, const float* __restrict__ vw,
    const float* __restrict__ ow,
    ushort* __restrict__ Xbf, ushort* __restrict__ Wbf)
{
    const int blk = blockIdx.x;
    const float* s; ushort* d; size_t base;
    if (blk < 4096)      { s = x;  d = Xbf;             base = (size_t)blk * 1024; }
    else if (blk < 5120) { s = qw; d = Wbf;             base = (size_t)(blk - 4096) * 1024; }
    else if (blk < 6144) { s = kw; d = Wbf + 1048576;   base = (size_t)(blk - 5120) * 1024; }
    else if (blk < 7168) { s = vw; d = Wbf + 2097152;   base = (size_t)(blk - 6144) * 1024; }
    else                 { s = ow; d = Wbf + 3145728;   base = (size_t)(blk - 7168) * 1024; }
    const size_t i = base + threadIdx.x * 4;
    float4 v = *(const float4*)(s + i);
    ushort4 o;
    o.x = f2bf(v.x); o.y = f2bf(v.y); o.z = f2bf(v.z); o.w = f2bf(v.w);
    *(ushort4*)(d + i) = o;
}

// ---------------------------------------------------------------------------
// V transpose (FALLBACK PATH ONLY)
// ---------------------------------------------------------------------------
__global__ __launch_bounds__(256) void transpose_v(
    const ushort* __restrict__ Vrow, ushort* __restrict__ Vt)
{
    __shared__ ushort T[64][72];
    const int tid  = threadIdx.x;
    const int tile = blockIdx.x;
    const int bh   = blockIdx.y;
    const int b = bh >> 4, h = bh & 15;

    #pragma unroll
    for (int rep = 0; rep < 2; ++rep) {
        int ch = tid + rep * 256;
        int tok = ch >> 3, seg = ch & 7;
        uint4 v = *(const uint4*)(Vrow + (size_t)(b * QLEN + tile * 64 + tok) * DIM
                                        + h * DH + seg * 8);
        *(uint4*)&T[tok][seg * 8] = v;
    }
    __syncthreads();
    #pragma unroll
    for (int rep = 0; rep < 2; ++rep) {
        int ch = tid + rep * 256;
        int dim = ch >> 3, tseg = ch & 7;
        ushort t0 = T[tseg * 8 + 0][dim], t1 = T[tseg * 8 + 1][dim];
        ushort t2 = T[tseg * 8 + 2][dim], t3 = T[tseg * 8 + 3][dim];
        ushort t4 = T[tseg * 8 + 4][dim], t5 = T[tseg * 8 + 5][dim];
        ushort t6 = T[tseg * 8 + 6][dim], t7 = T[tseg * 8 + 7][dim];
        uint4 o;
        o.x = (unsigned)t0 | ((unsigned)t1 << 16);
        o.y = (unsigned)t2 | ((unsigned)t3 << 16);
        o.z = (unsigned)t4 | ((unsigned)t5 << 16);
        o.w = (unsigned)t6 | ((unsigned)t7 << 16);
        *(uint4*)(Vt + (size_t)bh * DH * QLEN + (size_t)dim * QLEN
                      + tile * 64 + tseg * 8) = o;
    }
}

// ---------------------------------------------------------------------------
// QKV GEMM: 128x128 tile, BK=64 (16 barrier pairs), 4 waves of 64x64. N=3072.
// Staging: 1024 chunks(16B)/matrix, 4/thread, row-XOR seg swizzle
//   phys chunk ch -> row=ch>>3, pseg=ch&7, global seg g = pseg ^ (row&7).
// Frag read (k-half h): phys seg = (h*4+quad) ^ (r15&7)  -> 2-way, free.
// Epilogue: Q (scaled), K row-major, V transposed into Vt[bh][dim][token].
// ---------------------------------------------------------------------------
__global__ __launch_bounds__(256) void gemm_qkv(
    const ushort* __restrict__ A, const ushort* __restrict__ Bw,
    const float* __restrict__ bias0, const float* __restrict__ bias1,
    const float* __restrict__ bias2,
    ushort* __restrict__ outQ, ushort* __restrict__ outK, ushort* __restrict__ outVt)
{
    __shared__ ushort As[128 * 64];
    __shared__ ushort Bs[128 * 64];
    const int tid  = threadIdx.x;
    const int w    = tid >> 6;
    const int lane = tid & 63;
    const int r15  = lane & 15;
    const int quad = lane >> 4;
    const int nblk = 3072 >> 7;   // 24
    const int brow = blockIdx.x / nblk;
    const int bcol = blockIdx.x - brow * nblk;
    const int wrow = (w >> 1) * 64;
    const int wcol = (w & 1) * 64;
    const int K = DIM;

    float4_t acc[4][4];
    #pragma unroll
    for (int i = 0; i < 4; ++i)
        #pragma unroll
        for (int j = 0; j < 4; ++j)
            acc[i][j] = (float4_t){0.f, 0.f, 0.f, 0.f};

    // staging chunks: 4 per thread per matrix
    int chS[4];
    const ushort* gaS[4];
    const ushort* gbS[4];
    #pragma unroll
    for (int rep = 0; rep < 4; ++rep) {
        const int ch  = w * 256 + rep * 64 + lane;
        const int row = ch >> 3;
        const int g   = (ch & 7) ^ (row & 7);
        chS[rep] = ch;
        gaS[rep] = A  + (size_t)(brow * 128 + row) * K + g * 8;
        gbS[rep] = Bw + (size_t)(bcol * 128 + row) * K + g * 8;
    }
    const int xg = r15 & 7;   // frag seg xor

    for (int k0 = 0; k0 < K; k0 += 64) {
        __syncthreads();
        #pragma unroll
        for (int rep = 0; rep < 4; ++rep) {
            glds16(gaS[rep] + k0, As + chS[rep] * 8);
            glds16(gbS[rep] + k0, Bs + chS[rep] * 8);
        }
        __syncthreads();

        #pragma unroll
        for (int hh = 0; hh < 2; ++hh) {
            const int ph = ((hh * 4 + quad) ^ xg) * 8;
            short8 af[4], bf[4];
            #pragma unroll
            for (int ms = 0; ms < 4; ++ms)
                af[ms] = *(const short8*)&As[(wrow + ms * 16 + r15) * 64 + ph];
            #pragma unroll
            for (int ns = 0; ns < 4; ++ns)
                bf[ns] = *(const short8*)&Bs[(wcol + ns * 16 + r15) * 64 + ph];
            #pragma unroll
            for (int ms = 0; ms < 4; ++ms)
                #pragma unroll
                for (int ns = 0; ns < 4; ++ns)
                    acc[ms][ns] = __builtin_amdgcn_mfma_f32_16x16x32_bf16(
                        af[ms], bf[ns], acc[ms][ns], 0, 0, 0);
        }
    }

    #pragma unroll
    for (int ms = 0; ms < 4; ++ms) {
        const int rowg = brow * 128 + wrow + ms * 16 + quad * 4;   // token, 4-aligned
        #pragma unroll
        for (int ns = 0; ns < 4; ++ns) {
            const int colg = bcol * 128 + wcol + ns * 16 + r15;
            if (colg < 1024) {
                const float bb = bias0[colg];
                #pragma unroll
                for (int r = 0; r < 4; ++r)
                    outQ[(size_t)(rowg + r) * 1024 + colg] =
                        f2bf((acc[ms][ns][r] + bb) * QSCALE);
            } else if (colg < 2048) {
                const float bb = bias1[colg - 1024];
                #pragma unroll
                for (int r = 0; r < 4; ++r)
                    outK[(size_t)(rowg + r) * 1024 + (colg - 1024)] =
                        f2bf(acc[ms][ns][r] + bb);
            } else {
                const int vcol = colg - 2048;
                const int hh = vcol >> 6, dd = vcol & 63;
                const float bb = bias2[vcol];
                const int bidx = rowg >> 11;
                const int tloc = rowg & 2047;
                ushort4 o4;
                o4.x = f2bf(acc[ms][ns][0] + bb);
                o4.y = f2bf(acc[ms][ns][1] + bb);
                o4.z = f2bf(acc[ms][ns][2] + bb);
                o4.w = f2bf(acc[ms][ns][3] + bb);
                *(ushort4*)&outVt[((size_t)(bidx * 16 + hh) * 64 + dd) * QLEN + tloc] = o4;
            }
        }
    }
}

// ---------------------------------------------------------------------------
// O-projection GEMM: 128x64 tile, BK=64, 4 waves of 32x64. 512 blocks.
// ---------------------------------------------------------------------------
__global__ __launch_bounds__(256) void gemm_o(
    const ushort* __restrict__ A, const ushort* __restrict__ Bw,
    const float* __restrict__ bias, float* __restrict__ Out)
{
    __shared__ ushort As[128 * 64];
    __shared__ ushort Bs[64 * 64];
    const int tid  = threadIdx.x;
    const int w    = tid >> 6;
    const int lane = tid & 63;
    const int r15  = lane & 15;
    const int quad = lane >> 4;
    const int brow = blockIdx.x >> 4;
    const int bcol = blockIdx.x & 15;
    const int wrow = w * 32;
    const int K = DIM;

    float4_t acc[2][4];
    #pragma unroll
    for (int i = 0; i < 2; ++i)
        #pragma unroll
        for (int j = 0; j < 4; ++j)
            acc[i][j] = (float4_t){0.f, 0.f, 0.f, 0.f};

    int chA[4];  const ushort* gaS[4];
    #pragma unroll
    for (int rep = 0; rep < 4; ++rep) {
        const int ch  = w * 256 + rep * 64 + lane;
        const int row = ch >> 3;
        const int g   = (ch & 7) ^ (row & 7);
        chA[rep] = ch;
        gaS[rep] = A + (size_t)(brow * 128 + row) * K + g * 8;
    }
    int chB[2];  const ushort* gbS[2];
    #pragma unroll
    for (int rep = 0; rep < 2; ++rep) {
        const int ch  = w * 128 + rep * 64 + lane;
        const int row = ch >> 3;
        const int g   = (ch & 7) ^ (row & 7);
        chB[rep] = ch;
        gbS[rep] = Bw + (size_t)(bcol * 64 + row) * K + g * 8;
    }
    const int xg = r15 & 7;

    for (int k0 = 0; k0 < K; k0 += 64) {
        __syncthreads();
        #pragma unroll
        for (int rep = 0; rep < 4; ++rep)
            glds16(gaS[rep] + k0, As + chA[rep] * 8);
        #pragma unroll
        for (int rep = 0; rep < 2; ++rep)
            glds16(gbS[rep] + k0, Bs + chB[rep] * 8);
        __syncthreads();

        #pragma unroll
        for (int hh = 0; hh < 2; ++hh) {
            const int ph = ((hh * 4 + quad) ^ xg) * 8;
            short8 af[2], bf[4];
            #pragma unroll
            for (int ms = 0; ms < 2; ++ms)
                af[ms] = *(const short8*)&As[(wrow + ms * 16 + r15) * 64 + ph];
            #pragma unroll
            for (int ns = 0; ns < 4; ++ns)
                bf[ns] = *(const short8*)&Bs[(ns * 16 + r15) * 64 + ph];
            #pragma unroll
            for (int ms = 0; ms < 2; ++ms)
                #pragma unroll
                for (int ns = 0; ns < 4; ++ns)
                    acc[ms][ns] = __builtin_amdgcn_mfma_f32_16x16x32_bf16(
                        af[ms], bf[ns], acc[ms][ns], 0, 0, 0);
        }
    }

    #pragma unroll
    for (int ms = 0; ms < 2; ++ms) {
        const int rowg = brow * 128 + wrow + ms * 16 + quad * 4;
        #pragma unroll
        for (int ns = 0; ns < 4; ++ns) {
            const int colg = bcol * 64 + ns * 16 + r15;
            const float bb = bias[colg];
            #pragma unroll
            for (int r = 0; r < 4; ++r)
                Out[(size_t)(rowg + r) * 1024 + colg] = acc[ms][ns][r] + bb;
        }
    }
}

// ---------------------------------------------------------------------------
// Fallback GEMMs (fp32 inputs, 16x16/wave) for ws_size < 32MB.
// ---------------------------------------------------------------------------
__global__ __launch_bounds__(256) void gemm_f32in_bf16out(
    const float* __restrict__ X, const float* __restrict__ W,
    const float* __restrict__ B, ushort* __restrict__ Out,
    int M, int N, int K, float scale)
{
    const int lane = threadIdx.x & 63;
    const int wid  = (blockIdx.x * blockDim.x + threadIdx.x) >> 6;
    const int tilesN = N >> 4;
    const int tm = wid / tilesN;
    const int tn = wid - tm * tilesN;
    const int r15  = lane & 15;
    const int quad = lane >> 4;

    const float* xp = X + (size_t)(tm * 16 + r15) * K + quad * 8;
    const float* wp = W + (size_t)(tn * 16 + r15) * K + quad * 8;

    float4_t acc = {0.f, 0.f, 0.f, 0.f};
    for (int k0 = 0; k0 < K; k0 += 32) {
        float4 a0 = *(const float4*)(xp + k0);
        float4 a1 = *(const float4*)(xp + k0 + 4);
        float4 b0 = *(const float4*)(wp + k0);
        float4 b1 = *(const float4*)(wp + k0 + 4);
        acc = __builtin_amdgcn_mfma_f32_16x16x32_bf16(pack8(a0, a1), pack8(b0, b1), acc, 0, 0, 0);
    }
    const int col  = tn * 16 + r15;
    const float bias = B[col];
    const int row0 = tm * 16 + quad * 4;
    #pragma unroll
    for (int r = 0; r < 4; ++r)
        Out[(size_t)(row0 + r) * N + col] = f2bf((acc[r] + bias) * scale);
}

__global__ __launch_bounds__(256) void gemm_bf16in_f32out(
    const ushort* __restrict__ X, const float* __restrict__ W,
    const float* __restrict__ B, float* __restrict__ Out,
    int M, int N, int K)
{
    const int lane = threadIdx.x & 63;
    const int wid  = (blockIdx.x * blockDim.x + threadIdx.x) >> 6;
    const int tilesN = N >> 4;
    const int tm = wid / tilesN;
    const int tn = wid - tm * tilesN;
    const int r15  = lane & 15;
    const int quad = lane >> 4;

    const ushort* xp = X + (size_t)(tm * 16 + r15) * K + quad * 8;
    const float*  wp = W + (size_t)(tn * 16 + r15) * K + quad * 8;

    float4_t acc = {0.f, 0.f, 0.f, 0.f};
    for (int k0 = 0; k0 < K; k0 += 32) {
        short8 a = *(const short8*)(xp + k0);
        float4 b0 = *(const float4*)(wp + k0);
        float4 b1 = *(const float4*)(wp + k0 + 4);
        acc = __builtin_amdgcn_mfma_f32_16x16x32_bf16(a, pack8(b0, b1), acc, 0, 0, 0);
    }
    const int col  = tn * 16 + r15;
    const float bias = B[col];
    const int row0 = tm * 16 + quad * 4;
    #pragma unroll
    for (int r = 0; r < 4; ++r)
        Out[(size_t)(row0 + r) * N + col] = acc[r] + bias;
}

// ---------------------------------------------------------------------------
// Flash attention v6. grid (16 q-tiles, 32 bh), 4 waves; 32 q-rows per wave.
// r7 body (unconditional mask add — fast-path reverted) + 2-tile ILP:
// both LDS buffers are COMPUTE operands each iteration (two independent
// QK->exp->PV chains per wave), next pair register-prefetched.
// ---------------------------------------------------------------------------
__global__ __launch_bounds__(256) void flash_attn(
    const ushort* __restrict__ Qb, const ushort* __restrict__ Kb,
    const ushort* __restrict__ Vt, const int* __restrict__ mask,
    ushort* __restrict__ Cb)
{
    __shared__ __align__(16) ushort Ks[2][64][64];  // permuted key rows
    __shared__ __align__(16) ushort Vs[2][64][64];  // [dim][key]
    __shared__ __align__(16) float  Mb[QLEN];       // additive mask bias

    const int tid  = threadIdx.x;
    const int w    = tid >> 6;
    const int lane = tid & 63;
    const int r15  = lane & 15;
    const int quad = lane >> 4;
    const int bh = blockIdx.y;
    const int b = bh >> 4, h = bh & 15;

    {   // mask bias staging
        const int4* m4 = (const int4*)(mask + b * QLEN);
        #pragma unroll
        for (int rep = 0; rep < 2; ++rep) {
            const int idx = tid + rep * 256;
            int4 mv = m4[idx];
            float4 o;
            o.x = mv.x ? 0.f : -INFINITY;
            o.y = mv.y ? 0.f : -INFINITY;
            o.z = mv.z ? 0.f : -INFINITY;
            o.w = mv.w ? 0.f : -INFINITY;
            *(float4*)&Mb[idx * 4] = o;
        }
    }

    // Q B-frags (persistent)
    const int qbase = blockIdx.x * 128 + w * 32;
    const ushort* qp = Qb + (size_t)(b * QLEN + qbase + r15) * DIM + h * DH + quad * 8;
    short8 qf[2][2];
    qf[0][0] = *(const short8*)(qp);
    qf[0][1] = *(const short8*)(qp + 32);
    qf[1][0] = *(const short8*)(qp + 16 * DIM);
    qf[1][1] = *(const short8*)(qp + 16 * DIM + 32);

    const ushort* kg = Kb + (size_t)b * QLEN * DIM + h * DH;
    const ushort* vg = Vt + (size_t)bh * DH * QLEN;

    const int a0 = tid >> 3, seg = tid & 7;
    const int krow0 = (((a0 & 7) >> 2) << 4) + (((a0 >> 3) & 3) << 2) + (a0 & 3);
    const int sK = (seg ^ (krow0 & 7)) << 3;
    const int sV = (seg ^ (a0 & 7)) << 3;
    const int xq = (quad ^ (r15 & 7)) << 3;

    float4_t o[2][4];
    float4_t ol[2];
    #pragma unroll
    for (int rg = 0; rg < 2; ++rg) {
        ol[rg] = (float4_t){0.f, 0.f, 0.f, 0.f};
        #pragma unroll
        for (int ds = 0; ds < 4; ++ds)
            o[rg][ds] = (float4_t){0.f, 0.f, 0.f, 0.f};
    }
    short8 ones8;
    #pragma unroll
    for (int i = 0; i < 8; ++i) ones8[i] = (short)0x3F80;   // bf16 1.0

    // load tiles 0,1 -> regs -> LDS bufs 0,1
    uint4 kr[2][2], vr[2][2];
    #pragma unroll
    for (int tt = 0; tt < 2; ++tt) {
        kr[tt][0] = *(const uint4*)(kg + (size_t)(tt * 64 + a0     ) * DIM + seg * 8);
        kr[tt][1] = *(const uint4*)(kg + (size_t)(tt * 64 + a0 + 32) * DIM + seg * 8);
        vr[tt][0] = *(const uint4*)(vg + (size_t)(a0     ) * QLEN + tt * 64 + seg * 8);
        vr[tt][1] = *(const uint4*)(vg + (size_t)(a0 + 32) * QLEN + tt * 64 + seg * 8);
    }
    #pragma unroll
    for (int tt = 0; tt < 2; ++tt) {
        *(uint4*)&Ks[tt][krow0     ][sK] = kr[tt][0];
        *(uint4*)&Ks[tt][krow0 + 32][sK] = kr[tt][1];
        *(uint4*)&Vs[tt][a0        ][sV] = vr[tt][0];
        *(uint4*)&Vs[tt][a0 + 32   ][sV] = vr[tt][1];
    }
    __syncthreads();

    for (int kt = 0; kt < QLEN; kt += 128) {
        const bool more = (kt + 128 < QLEN);
        if (more) {   // prefetch next pair into registers
            const int ktn = kt + 128;
            #pragma unroll
            for (int tt = 0; tt < 2; ++tt) {
                kr[tt][0] = *(const uint4*)(kg + (size_t)(ktn + tt * 64 + a0     ) * DIM + seg * 8);
                kr[tt][1] = *(const uint4*)(kg + (size_t)(ktn + tt * 64 + a0 + 32) * DIM + seg * 8);
                vr[tt][0] = *(const uint4*)(vg + (size_t)(a0     ) * QLEN + ktn + tt * 64 + seg * 8);
                vr[tt][1] = *(const uint4*)(vg + (size_t)(a0 + 32) * QLEN + ktn + tt * 64 + seg * 8);
            }
        }

        // ---- two independent compute chains (tiles kt, kt+64) ----
        #pragma unroll
        for (int tt = 0; tt < 2; ++tt) {
            const int ktt = kt + tt * 64;
            int pk[4][2][2];   // [ks][rg][h]
            #pragma unroll
            for (int ks = 0; ks < 4; ++ks) {
                const ushort* krow = &Ks[tt][ks * 16 + r15][0];
                short8 kf0 = *(const short8*)(krow + xq);
                short8 kf1 = *(const short8*)(krow + (xq ^ 32));
                const float4 mb = *(const float4*)&Mb[ktt + ((ks >> 1) << 5)
                                                       + (quad << 3) + ((ks & 1) << 2)];
                #pragma unroll
                for (int rg = 0; rg < 2; ++rg) {
                    float4_t s = {0.f, 0.f, 0.f, 0.f};
                    s = __builtin_amdgcn_mfma_f32_16x16x32_bf16(kf0, qf[rg][0], s, 0, 0, 0);
                    s = __builtin_amdgcn_mfma_f32_16x16x32_bf16(kf1, qf[rg][1], s, 0, 0, 0);
                    unsigned u0 = __float_as_uint(__builtin_amdgcn_exp2f(s[0] + mb.x));
                    unsigned u1 = __float_as_uint(__builtin_amdgcn_exp2f(s[1] + mb.y));
                    unsigned u2 = __float_as_uint(__builtin_amdgcn_exp2f(s[2] + mb.z));
                    unsigned u3 = __float_as_uint(__builtin_amdgcn_exp2f(s[3] + mb.w));
                    pk[ks][rg][0] = __builtin_amdgcn_perm(u1, u0, 0x07060302);
                    pk[ks][rg][1] = __builtin_amdgcn_perm(u3, u2, 0x07060302);
                }
            }
            #pragma unroll
            for (int ck = 0; ck < 2; ++ck) {
                short8 vf[4];
                #pragma unroll
                for (int ds = 0; ds < 4; ++ds)
                    vf[ds] = *(const short8*)(&Vs[tt][ds * 16 + r15][0] + (xq ^ (ck << 5)));
                #pragma unroll
                for (int rg = 0; rg < 2; ++rg) {
                    int4_t pfi = { pk[2 * ck][rg][0], pk[2 * ck][rg][1],
                                   pk[2 * ck + 1][rg][0], pk[2 * ck + 1][rg][1] };
                    short8 pf = __builtin_bit_cast(short8, pfi);
                    #pragma unroll
                    for (int ds = 0; ds < 4; ++ds)
                        o[rg][ds] = __builtin_amdgcn_mfma_f32_16x16x32_bf16(
                            pf, vf[ds], o[rg][ds], 0, 0, 0);
                    ol[rg] = __builtin_amdgcn_mfma_f32_16x16x32_bf16(
                        pf, ones8, ol[rg], 0, 0, 0);
                }
            }
        }

        if (more) {
            __syncthreads();   // all readers done with bufs
            #pragma unroll
            for (int tt = 0; tt < 2; ++tt) {
                *(uint4*)&Ks[tt][krow0     ][sK] = kr[tt][0];
                *(uint4*)&Ks[tt][krow0 + 32][sK] = kr[tt][1];
                *(uint4*)&Vs[tt][a0        ][sV] = vr[tt][0];
                *(uint4*)&Vs[tt][a0 + 32   ][sV] = vr[tt][1];
            }
            __syncthreads();   // stores visible
        }
    }

    // ---- epilogue: normalize + write ----
    #pragma unroll
    for (int rg = 0; rg < 2; ++rg) {
        #pragma unroll
        for (int r = 0; r < 4; ++r) {
            const float ir = 1.f / fmaxf(ol[rg][r], 1e-30f);
            const size_t rb = (size_t)(b * QLEN + qbase + rg * 16 + quad * 4 + r) * DIM
                              + h * DH;
            Cb[rb +  0 + r15] = f2bf(o[rg][0][r] * ir);
            Cb[rb + 16 + r15] = f2bf(o[rg][1][r] * ir);
            Cb[rb + 32 + r15] = f2bf(o[rg][2][r] * ir);
            Cb[rb + 48 + r15] = f2bf(o[rg][3][r] * ir);
        }
    }
}

// ---------------------------------------------------------------------------
extern "C" void kernel_launch(void* const* d_in, const int* in_sizes, int n_in,
                              void* d_out, int out_size, void* d_ws, size_t ws_size,
                              hipStream_t stream)
{
    const float* x    = (const float*)d_in[0];
    const int*   mask = (const int*)d_in[1];
    const float* q_w  = (const float*)d_in[2];
    const float* q_b  = (const float*)d_in[3];
    const float* k_w  = (const float*)d_in[4];
    const float* k_b  = (const float*)d_in[5];
    const float* v_w  = (const float*)d_in[6];
    const float* v_b  = (const float*)d_in[7];
    const float* o_w  = (const float*)d_in[8];
    const float* o_b  = (const float*)d_in[9];
    float* out = (float*)d_out;

    const size_t SEG = (size_t)MTOK * DIM;        // 4M elements (8 MB bf16)
    ushort* Qbf = (ushort*)d_out;                 // d_out[0:8MB]
    ushort* Xbf = Qbf + SEG;                      // d_out[8:16MB]
    ushort* Kb  = (ushort*)d_ws;                  // ws[0:8MB]
    ushort* Cb  = Kb + SEG;                       // ws[8:16MB]
    ushort* Vt  = Cb + SEG;                       // ws[16:24MB]
    ushort* Wbf = Vt + SEG;                       // ws[24:32MB]

    const bool big = ws_size >= (size_t)32 * 1024 * 1024;

    if (big) {
        conv_all<<<8192, 256, 0, stream>>>(x, q_w, k_w, v_w, o_w, Xbf, Wbf);
        gemm_qkv<<<(MTOK / 128) * (3072 / 128), 256, 0, stream>>>(
            Xbf, Wbf, q_b, k_b, v_b, Qbf, Kb, Vt);
        flash_attn<<<dim3(QLEN / 128, BS * NH), 256, 0, stream>>>(Qbf, Kb, Vt, mask, Cb);
        gemm_o<<<(MTOK / 128) * (DIM / 64), 256, 0, stream>>>(
            Cb, Wbf + 3 * (size_t)(DIM * DIM), o_b, out);
    } else {
        const int tiles   = (MTOK / 16) * (DIM / 16);
        const int gblocks = tiles / 4;
        gemm_f32in_bf16out<<<gblocks, 256, 0, stream>>>(x, q_w, q_b, Qbf, MTOK, DIM, DIM, QSCALE);
        gemm_f32in_bf16out<<<gblocks, 256, 0, stream>>>(x, k_w, k_b, Kb,  MTOK, DIM, DIM, 1.0f);
        gemm_f32in_bf16out<<<gblocks, 256, 0, stream>>>(x, v_w, v_b, Cb,  MTOK, DIM, DIM, 1.0f);
        transpose_v<<<dim3(QLEN / 64, BS * NH), 256, 0, stream>>>(Cb, Vt);
        flash_attn<<<dim3(QLEN / 128, BS * NH), 256, 0, stream>>>(Qbf, Kb, Vt, mask, Cb);
        gemm_bf16in_f32out<<<tiles / 4, 256, 0, stream>>>(Cb, o_w, o_b, out, MTOK, DIM, DIM);
    }
}

// Round 10
// 201.089 us; speedup vs baseline: 1.2186x; 1.2186x over previous
//
#include <hip/hip_runtime.h>

// ---------------------------------------------------------------------------
// MultiHeadAttention — fp32 in/out, bf16 compute.
// Round 10: flash reverted to r7 body (r9's 2-tile ILP spilled to scratch:
// WRITE_SIZE 8MB->229MB, dur 53.5->101us). GEMMs keep r9 BK=64 (saved ~13us).
// BS=2, QLEN=2048, DIM=1024, NH=16, DH=64.
// d_out (16 MB fp32): [ Q_bf16 8MB | X_bf16 8MB ]  (dead before O-GEMM writes)
// d_ws  (>=32MB):     [ K_bf16 8MB | C_bf16 8MB | Vt 8MB | W_bf16 8MB ]
// ---------------------------------------------------------------------------

#define BS    2
#define QLEN  2048
#define DIM   1024
#define NH    16
#define DH    64
#define MTOK  (BS * QLEN)          // 4096 token rows

// Q projection scale: (1/8) * log2(e) so attention uses exp2 directly.
#define QSCALE 0.18033688011112042f

typedef __attribute__((ext_vector_type(8))) short short8;   // 8 bf16
typedef __attribute__((ext_vector_type(4))) float float4_t; // MFMA acc
typedef __attribute__((ext_vector_type(4))) int   int4_t;

__device__ __forceinline__ ushort f2bf(float f) {   // RNE
    unsigned u = __float_as_uint(f);
    return (ushort)((u + 0x7fffu + ((u >> 16) & 1u)) >> 16);
}
__device__ __forceinline__ short8 pack8(float4 a0, float4 a1) {
    short8 r;
    r[0] = (short)f2bf(a0.x); r[1] = (short)f2bf(a0.y);
    r[2] = (short)f2bf(a0.z); r[3] = (short)f2bf(a0.w);
    r[4] = (short)f2bf(a1.x); r[5] = (short)f2bf(a1.y);
    r[6] = (short)f2bf(a1.z); r[7] = (short)f2bf(a1.w);
    return r;
}

// async global->LDS, 16 B per lane (lds dest = wave-uniform base + lane*16).
__device__ __forceinline__ void glds16(const void* g, void* l) {
    __builtin_amdgcn_global_load_lds(
        (const __attribute__((address_space(1))) unsigned int*)g,
        (__attribute__((address_space(3))) unsigned int*)l, 16, 0, 0);
}

// ---------------------------------------------------------------------------
// Combined fp32 -> bf16 convert: X (4M) + 4 weights (1M each), one launch.
// ---------------------------------------------------------------------------
__global__ __launch_bounds__(256) void conv_all(
    const float* __restrict__ x,  const float* __restrict__ qw,
    const float* __restrict__ kw, const float* __restrict__ vw,
    const float* __restrict__ ow,
    ushort* __restrict__ Xbf, ushort* __restrict__ Wbf)
{
    const int blk = blockIdx.x;
    const float* s; ushort* d; size_t base;
    if (blk < 4096)      { s = x;  d = Xbf;             base = (size_t)blk * 1024; }
    else if (blk < 5120) { s = qw; d = Wbf;             base = (size_t)(blk - 4096) * 1024; }
    else if (blk < 6144) { s = kw; d = Wbf + 1048576;   base = (size_t)(blk - 5120) * 1024; }
    else if (blk < 7168) { s = vw; d = Wbf + 2097152;   base = (size_t)(blk - 6144) * 1024; }
    else                 { s = ow; d = Wbf + 3145728;   base = (size_t)(blk - 7168) * 1024; }
    const size_t i = base + threadIdx.x * 4;
    float4 v = *(const float4*)(s + i);
    ushort4 o;
    o.x = f2bf(v.x); o.y = f2bf(v.y); o.z = f2bf(v.z); o.w = f2bf(v.w);
    *(ushort4*)(d + i) = o;
}

// ---------------------------------------------------------------------------
// V transpose (FALLBACK PATH ONLY)
// ---------------------------------------------------------------------------
__global__ __launch_bounds__(256) void transpose_v(
    const ushort* __restrict__ Vrow, ushort* __restrict__ Vt)
{
    __shared__ ushort T[64][72];
    const int tid  = threadIdx.x;
    const int tile = blockIdx.x;
    const int bh   = blockIdx.y;
    const int b = bh >> 4, h = bh & 15;

    #pragma unroll
    for (int rep = 0; rep < 2; ++rep) {
        int ch = tid + rep * 256;
        int tok = ch >> 3, seg = ch & 7;
        uint4 v = *(const uint4*)(Vrow + (size_t)(b * QLEN + tile * 64 + tok) * DIM
                                        + h * DH + seg * 8);
        *(uint4*)&T[tok][seg * 8] = v;
    }
    __syncthreads();
    #pragma unroll
    for (int rep = 0; rep < 2; ++rep) {
        int ch = tid + rep * 256;
        int dim = ch >> 3, tseg = ch & 7;
        ushort t0 = T[tseg * 8 + 0][dim], t1 = T[tseg * 8 + 1][dim];
        ushort t2 = T[tseg * 8 + 2][dim], t3 = T[tseg * 8 + 3][dim];
        ushort t4 = T[tseg * 8 + 4][dim], t5 = T[tseg * 8 + 5][dim];
        ushort t6 = T[tseg * 8 + 6][dim], t7 = T[tseg * 8 + 7][dim];
        uint4 o;
        o.x = (unsigned)t0 | ((unsigned)t1 << 16);
        o.y = (unsigned)t2 | ((unsigned)t3 << 16);
        o.z = (unsigned)t4 | ((unsigned)t5 << 16);
        o.w = (unsigned)t6 | ((unsigned)t7 << 16);
        *(uint4*)(Vt + (size_t)bh * DH * QLEN + (size_t)dim * QLEN
                      + tile * 64 + tseg * 8) = o;
    }
}

// ---------------------------------------------------------------------------
// QKV GEMM: 128x128 tile, BK=64 (16 barrier pairs), 4 waves of 64x64. N=3072.
// Staging: 1024 chunks(16B)/matrix, 4/thread, row-XOR seg swizzle.
// Epilogue: Q (scaled), K row-major, V transposed into Vt[bh][dim][token].
// ---------------------------------------------------------------------------
__global__ __launch_bounds__(256) void gemm_qkv(
    const ushort* __restrict__ A, const ushort* __restrict__ Bw,
    const float* __restrict__ bias0, const float* __restrict__ bias1,
    const float* __restrict__ bias2,
    ushort* __restrict__ outQ, ushort* __restrict__ outK, ushort* __restrict__ outVt)
{
    __shared__ ushort As[128 * 64];
    __shared__ ushort Bs[128 * 64];
    const int tid  = threadIdx.x;
    const int w    = tid >> 6;
    const int lane = tid & 63;
    const int r15  = lane & 15;
    const int quad = lane >> 4;
    const int nblk = 3072 >> 7;   // 24
    const int brow = blockIdx.x / nblk;
    const int bcol = blockIdx.x - brow * nblk;
    const int wrow = (w >> 1) * 64;
    const int wcol = (w & 1) * 64;
    const int K = DIM;

    float4_t acc[4][4];
    #pragma unroll
    for (int i = 0; i < 4; ++i)
        #pragma unroll
        for (int j = 0; j < 4; ++j)
            acc[i][j] = (float4_t){0.f, 0.f, 0.f, 0.f};

    int chS[4];
    const ushort* gaS[4];
    const ushort* gbS[4];
    #pragma unroll
    for (int rep = 0; rep < 4; ++rep) {
        const int ch  = w * 256 + rep * 64 + lane;
        const int row = ch >> 3;
        const int g   = (ch & 7) ^ (row & 7);
        chS[rep] = ch;
        gaS[rep] = A  + (size_t)(brow * 128 + row) * K + g * 8;
        gbS[rep] = Bw + (size_t)(bcol * 128 + row) * K + g * 8;
    }
    const int xg = r15 & 7;   // frag seg xor

    for (int k0 = 0; k0 < K; k0 += 64) {
        __syncthreads();
        #pragma unroll
        for (int rep = 0; rep < 4; ++rep) {
            glds16(gaS[rep] + k0, As + chS[rep] * 8);
            glds16(gbS[rep] + k0, Bs + chS[rep] * 8);
        }
        __syncthreads();

        #pragma unroll
        for (int hh = 0; hh < 2; ++hh) {
            const int ph = ((hh * 4 + quad) ^ xg) * 8;
            short8 af[4], bf[4];
            #pragma unroll
            for (int ms = 0; ms < 4; ++ms)
                af[ms] = *(const short8*)&As[(wrow + ms * 16 + r15) * 64 + ph];
            #pragma unroll
            for (int ns = 0; ns < 4; ++ns)
                bf[ns] = *(const short8*)&Bs[(wcol + ns * 16 + r15) * 64 + ph];
            #pragma unroll
            for (int ms = 0; ms < 4; ++ms)
                #pragma unroll
                for (int ns = 0; ns < 4; ++ns)
                    acc[ms][ns] = __builtin_amdgcn_mfma_f32_16x16x32_bf16(
                        af[ms], bf[ns], acc[ms][ns], 0, 0, 0);
        }
    }

    #pragma unroll
    for (int ms = 0; ms < 4; ++ms) {
        const int rowg = brow * 128 + wrow + ms * 16 + quad * 4;   // token, 4-aligned
        #pragma unroll
        for (int ns = 0; ns < 4; ++ns) {
            const int colg = bcol * 128 + wcol + ns * 16 + r15;
            if (colg < 1024) {
                const float bb = bias0[colg];
                #pragma unroll
                for (int r = 0; r < 4; ++r)
                    outQ[(size_t)(rowg + r) * 1024 + colg] =
                        f2bf((acc[ms][ns][r] + bb) * QSCALE);
            } else if (colg < 2048) {
                const float bb = bias1[colg - 1024];
                #pragma unroll
                for (int r = 0; r < 4; ++r)
                    outK[(size_t)(rowg + r) * 1024 + (colg - 1024)] =
                        f2bf(acc[ms][ns][r] + bb);
            } else {
                const int vcol = colg - 2048;
                const int hh = vcol >> 6, dd = vcol & 63;
                const float bb = bias2[vcol];
                const int bidx = rowg >> 11;
                const int tloc = rowg & 2047;
                ushort4 o4;
                o4.x = f2bf(acc[ms][ns][0] + bb);
                o4.y = f2bf(acc[ms][ns][1] + bb);
                o4.z = f2bf(acc[ms][ns][2] + bb);
                o4.w = f2bf(acc[ms][ns][3] + bb);
                *(ushort4*)&outVt[((size_t)(bidx * 16 + hh) * 64 + dd) * QLEN + tloc] = o4;
            }
        }
    }
}

// ---------------------------------------------------------------------------
// O-projection GEMM: 128x64 tile, BK=64, 4 waves of 32x64. 512 blocks.
// ---------------------------------------------------------------------------
__global__ __launch_bounds__(256) void gemm_o(
    const ushort* __restrict__ A, const ushort* __restrict__ Bw,
    const float* __restrict__ bias, float* __restrict__ Out)
{
    __shared__ ushort As[128 * 64];
    __shared__ ushort Bs[64 * 64];
    const int tid  = threadIdx.x;
    const int w    = tid >> 6;
    const int lane = tid & 63;
    const int r15  = lane & 15;
    const int quad = lane >> 4;
    const int brow = blockIdx.x >> 4;
    const int bcol = blockIdx.x & 15;
    const int wrow = w * 32;
    const int K = DIM;

    float4_t acc[2][4];
    #pragma unroll
    for (int i = 0; i < 2; ++i)
        #pragma unroll
        for (int j = 0; j < 4; ++j)
            acc[i][j] = (float4_t){0.f, 0.f, 0.f, 0.f};

    int chA[4];  const ushort* gaS[4];
    #pragma unroll
    for (int rep = 0; rep < 4; ++rep) {
        const int ch  = w * 256 + rep * 64 + lane;
        const int row = ch >> 3;
        const int g   = (ch & 7) ^ (row & 7);
        chA[rep] = ch;
        gaS[rep] = A + (size_t)(brow * 128 + row) * K + g * 8;
    }
    int chB[2];  const ushort* gbS[2];
    #pragma unroll
    for (int rep = 0; rep < 2; ++rep) {
        const int ch  = w * 128 + rep * 64 + lane;
        const int row = ch >> 3;
        const int g   = (ch & 7) ^ (row & 7);
        chB[rep] = ch;
        gbS[rep] = Bw + (size_t)(bcol * 64 + row) * K + g * 8;
    }
    const int xg = r15 & 7;

    for (int k0 = 0; k0 < K; k0 += 64) {
        __syncthreads();
        #pragma unroll
        for (int rep = 0; rep < 4; ++rep)
            glds16(gaS[rep] + k0, As + chA[rep] * 8);
        #pragma unroll
        for (int rep = 0; rep < 2; ++rep)
            glds16(gbS[rep] + k0, Bs + chB[rep] * 8);
        __syncthreads();

        #pragma unroll
        for (int hh = 0; hh < 2; ++hh) {
            const int ph = ((hh * 4 + quad) ^ xg) * 8;
            short8 af[2], bf[4];
            #pragma unroll
            for (int ms = 0; ms < 2; ++ms)
                af[ms] = *(const short8*)&As[(wrow + ms * 16 + r15) * 64 + ph];
            #pragma unroll
            for (int ns = 0; ns < 4; ++ns)
                bf[ns] = *(const short8*)&Bs[(ns * 16 + r15) * 64 + ph];
            #pragma unroll
            for (int ms = 0; ms < 2; ++ms)
                #pragma unroll
                for (int ns = 0; ns < 4; ++ns)
                    acc[ms][ns] = __builtin_amdgcn_mfma_f32_16x16x32_bf16(
                        af[ms], bf[ns], acc[ms][ns], 0, 0, 0);
        }
    }

    #pragma unroll
    for (int ms = 0; ms < 2; ++ms) {
        const int rowg = brow * 128 + wrow + ms * 16 + quad * 4;
        #pragma unroll
        for (int ns = 0; ns < 4; ++ns) {
            const int colg = bcol * 64 + ns * 16 + r15;
            const float bb = bias[colg];
            #pragma unroll
            for (int r = 0; r < 4; ++r)
                Out[(size_t)(rowg + r) * 1024 + colg] = acc[ms][ns][r] + bb;
        }
    }
}

// ---------------------------------------------------------------------------
// Fallback GEMMs (fp32 inputs, 16x16/wave) for ws_size < 32MB.
// ---------------------------------------------------------------------------
__global__ __launch_bounds__(256) void gemm_f32in_bf16out(
    const float* __restrict__ X, const float* __restrict__ W,
    const float* __restrict__ B, ushort* __restrict__ Out,
    int M, int N, int K, float scale)
{
    const int lane = threadIdx.x & 63;
    const int wid  = (blockIdx.x * blockDim.x + threadIdx.x) >> 6;
    const int tilesN = N >> 4;
    const int tm = wid / tilesN;
    const int tn = wid - tm * tilesN;
    const int r15  = lane & 15;
    const int quad = lane >> 4;

    const float* xp = X + (size_t)(tm * 16 + r15) * K + quad * 8;
    const float* wp = W + (size_t)(tn * 16 + r15) * K + quad * 8;

    float4_t acc = {0.f, 0.f, 0.f, 0.f};
    for (int k0 = 0; k0 < K; k0 += 32) {
        float4 a0 = *(const float4*)(xp + k0);
        float4 a1 = *(const float4*)(xp + k0 + 4);
        float4 b0 = *(const float4*)(wp + k0);
        float4 b1 = *(const float4*)(wp + k0 + 4);
        acc = __builtin_amdgcn_mfma_f32_16x16x32_bf16(pack8(a0, a1), pack8(b0, b1), acc, 0, 0, 0);
    }
    const int col  = tn * 16 + r15;
    const float bias = B[col];
    const int row0 = tm * 16 + quad * 4;
    #pragma unroll
    for (int r = 0; r < 4; ++r)
        Out[(size_t)(row0 + r) * N + col] = f2bf((acc[r] + bias) * scale);
}

__global__ __launch_bounds__(256) void gemm_bf16in_f32out(
    const ushort* __restrict__ X, const float* __restrict__ W,
    const float* __restrict__ B, float* __restrict__ Out,
    int M, int N, int K)
{
    const int lane = threadIdx.x & 63;
    const int wid  = (blockIdx.x * blockDim.x + threadIdx.x) >> 6;
    const int tilesN = N >> 4;
    const int tm = wid / tilesN;
    const int tn = wid - tm * tilesN;
    const int r15  = lane & 15;
    const int quad = lane >> 4;

    const ushort* xp = X + (size_t)(tm * 16 + r15) * K + quad * 8;
    const float*  wp = W + (size_t)(tn * 16 + r15) * K + quad * 8;

    float4_t acc = {0.f, 0.f, 0.f, 0.f};
    for (int k0 = 0; k0 < K; k0 += 32) {
        short8 a = *(const short8*)(xp + k0);
        float4 b0 = *(const float4*)(wp + k0);
        float4 b1 = *(const float4*)(wp + k0 + 4);
        acc = __builtin_amdgcn_mfma_f32_16x16x32_bf16(a, pack8(b0, b1), acc, 0, 0, 0);
    }
    const int col  = tn * 16 + r15;
    const float bias = B[col];
    const int row0 = tm * 16 + quad * 4;
    #pragma unroll
    for (int r = 0; r < 4; ++r)
        Out[(size_t)(row0 + r) * N + col] = acc[r] + bias;
}

// ---------------------------------------------------------------------------
// Flash attention (r7 body — proven 53.5us, zero conflicts, no spill).
// grid (16 q-tiles, 32 bh), 4 waves; 32 q-rows per wave.
// S^T QK with permuted key->subtile assignment (C-regs == PV A-frags),
// l via ones-column MFMA, raw v_exp_f32, double-buffered XOR-swizzled LDS,
// single-tile loop with register prefetch (no 2-tile ILP: it spills).
// ---------------------------------------------------------------------------
__global__ __launch_bounds__(256) void flash_attn(
    const ushort* __restrict__ Qb, const ushort* __restrict__ Kb,
    const ushort* __restrict__ Vt, const int* __restrict__ mask,
    ushort* __restrict__ Cb)
{
    __shared__ __align__(16) ushort Ks[2][64][64];  // permuted key rows
    __shared__ __align__(16) ushort Vs[2][64][64];  // [dim][key]
    __shared__ __align__(16) float  Mb[QLEN];       // additive mask bias

    const int tid  = threadIdx.x;
    const int w    = tid >> 6;
    const int lane = tid & 63;
    const int r15  = lane & 15;
    const int quad = lane >> 4;
    const int bh = blockIdx.y;
    const int b = bh >> 4, h = bh & 15;

    {   // mask bias staging
        const int4* m4 = (const int4*)(mask + b * QLEN);
        #pragma unroll
        for (int rep = 0; rep < 2; ++rep) {
            const int idx = tid + rep * 256;
            int4 mv = m4[idx];
            float4 o;
            o.x = mv.x ? 0.f : -INFINITY;
            o.y = mv.y ? 0.f : -INFINITY;
            o.z = mv.z ? 0.f : -INFINITY;
            o.w = mv.w ? 0.f : -INFINITY;
            *(float4*)&Mb[idx * 4] = o;
        }
    }

    // Q B-frags (persistent)
    const int qbase = blockIdx.x * 128 + w * 32;
    const ushort* qp = Qb + (size_t)(b * QLEN + qbase + r15) * DIM + h * DH + quad * 8;
    short8 qf[2][2];
    qf[0][0] = *(const short8*)(qp);
    qf[0][1] = *(const short8*)(qp + 32);
    qf[1][0] = *(const short8*)(qp + 16 * DIM);
    qf[1][1] = *(const short8*)(qp + 16 * DIM + 32);

    const ushort* kg = Kb + (size_t)b * QLEN * DIM + h * DH;
    const ushort* vg = Vt + (size_t)bh * DH * QLEN;

    const int a0 = tid >> 3, seg = tid & 7;
    const int krow0 = (((a0 & 7) >> 2) << 4) + (((a0 >> 3) & 3) << 2) + (a0 & 3);
    const int sK = (seg ^ (krow0 & 7)) << 3;
    const int sV = (seg ^ (a0 & 7)) << 3;
    const int xq = (quad ^ (r15 & 7)) << 3;

    float4_t o[2][4];
    float4_t ol[2];
    #pragma unroll
    for (int rg = 0; rg < 2; ++rg) {
        ol[rg] = (float4_t){0.f, 0.f, 0.f, 0.f};
        #pragma unroll
        for (int ds = 0; ds < 4; ++ds)
            o[rg][ds] = (float4_t){0.f, 0.f, 0.f, 0.f};
    }
    short8 ones8;
    #pragma unroll
    for (int i = 0; i < 8; ++i) ones8[i] = (short)0x3F80;   // bf16 1.0

    // stage tile 0 into buffer 0
    uint4 kr0 = *(const uint4*)(kg + (size_t)(a0     ) * DIM + seg * 8);
    uint4 kr1 = *(const uint4*)(kg + (size_t)(a0 + 32) * DIM + seg * 8);
    uint4 vr0 = *(const uint4*)(vg + (size_t)(a0     ) * QLEN + seg * 8);
    uint4 vr1 = *(const uint4*)(vg + (size_t)(a0 + 32) * QLEN + seg * 8);
    *(uint4*)&Ks[0][krow0     ][sK] = kr0;
    *(uint4*)&Ks[0][krow0 + 32][sK] = kr1;
    *(uint4*)&Vs[0][a0        ][sV] = vr0;
    *(uint4*)&Vs[0][a0 + 32   ][sV] = vr1;
    __syncthreads();

    int p = 0;
    for (int kt = 0; kt < QLEN; kt += 64) {
        const bool more = (kt + 64 < QLEN);
        if (more) {   // prefetch next tile into registers
            kr0 = *(const uint4*)(kg + (size_t)(kt + 64 + a0     ) * DIM + seg * 8);
            kr1 = *(const uint4*)(kg + (size_t)(kt + 64 + a0 + 32) * DIM + seg * 8);
            vr0 = *(const uint4*)(vg + (size_t)(a0     ) * QLEN + kt + 64 + seg * 8);
            vr1 = *(const uint4*)(vg + (size_t)(a0 + 32) * QLEN + kt + 64 + seg * 8);
        }

        // ---- S^T per subtile; exp; pack into PV A-frag registers ----
        int pk[4][2][2];   // [ks][rg][h]
        #pragma unroll
        for (int ks = 0; ks < 4; ++ks) {
            const ushort* krow = &Ks[p][ks * 16 + r15][0];
            short8 kf0 = *(const short8*)(krow + xq);
            short8 kf1 = *(const short8*)(krow + (xq ^ 32));
            const float4 mb = *(const float4*)&Mb[kt + ((ks >> 1) << 5)
                                                   + (quad << 3) + ((ks & 1) << 2)];
            #pragma unroll
            for (int rg = 0; rg < 2; ++rg) {
                float4_t s = {0.f, 0.f, 0.f, 0.f};
                s = __builtin_amdgcn_mfma_f32_16x16x32_bf16(kf0, qf[rg][0], s, 0, 0, 0);
                s = __builtin_amdgcn_mfma_f32_16x16x32_bf16(kf1, qf[rg][1], s, 0, 0, 0);
                unsigned u0 = __float_as_uint(__builtin_amdgcn_exp2f(s[0] + mb.x));
                unsigned u1 = __float_as_uint(__builtin_amdgcn_exp2f(s[1] + mb.y));
                unsigned u2 = __float_as_uint(__builtin_amdgcn_exp2f(s[2] + mb.z));
                unsigned u3 = __float_as_uint(__builtin_amdgcn_exp2f(s[3] + mb.w));
                pk[ks][rg][0] = __builtin_amdgcn_perm(u1, u0, 0x07060302);
                pk[ks][rg][1] = __builtin_amdgcn_perm(u3, u2, 0x07060302);
            }
        }

        // ---- O += P @ V ; ol += P @ ones (row-sums = l) ----
        #pragma unroll
        for (int ck = 0; ck < 2; ++ck) {
            short8 vf[4];
            #pragma unroll
            for (int ds = 0; ds < 4; ++ds)
                vf[ds] = *(const short8*)(&Vs[p][ds * 16 + r15][0] + (xq ^ (ck << 5)));
            #pragma unroll
            for (int rg = 0; rg < 2; ++rg) {
                int4_t pfi = { pk[2 * ck][rg][0], pk[2 * ck][rg][1],
                               pk[2 * ck + 1][rg][0], pk[2 * ck + 1][rg][1] };
                short8 pf = __builtin_bit_cast(short8, pfi);
                #pragma unroll
                for (int ds = 0; ds < 4; ++ds)
                    o[rg][ds] = __builtin_amdgcn_mfma_f32_16x16x32_bf16(
                        pf, vf[ds], o[rg][ds], 0, 0, 0);
                ol[rg] = __builtin_amdgcn_mfma_f32_16x16x32_bf16(
                    pf, ones8, ol[rg], 0, 0, 0);
            }
        }

        // ---- store prefetched tile into the other buffer; single barrier ----
        if (more) {
            *(uint4*)&Ks[p ^ 1][krow0     ][sK] = kr0;
            *(uint4*)&Ks[p ^ 1][krow0 + 32][sK] = kr1;
            *(uint4*)&Vs[p ^ 1][a0        ][sV] = vr0;
            *(uint4*)&Vs[p ^ 1][a0 + 32   ][sV] = vr1;
        }
        __syncthreads();
        p ^= 1;
    }

    // ---- epilogue: normalize + write ----
    #pragma unroll
    for (int rg = 0; rg < 2; ++rg) {
        #pragma unroll
        for (int r = 0; r < 4; ++r) {
            const float ir = 1.f / fmaxf(ol[rg][r], 1e-30f);
            const size_t rb = (size_t)(b * QLEN + qbase + rg * 16 + quad * 4 + r) * DIM
                              + h * DH;
            Cb[rb +  0 + r15] = f2bf(o[rg][0][r] * ir);
            Cb[rb + 16 + r15] = f2bf(o[rg][1][r] * ir);
            Cb[rb + 32 + r15] = f2bf(o[rg][2][r] * ir);
            Cb[rb + 48 + r15] = f2bf(o[rg][3][r] * ir);
        }
    }
}

// ---------------------------------------------------------------------------
extern "C" void kernel_launch(void* const* d_in, const int* in_sizes, int n_in,
                              void* d_out, int out_size, void* d_ws, size_t ws_size,
                              hipStream_t stream)
{
    const float* x    = (const float*)d_in[0];
    const int*   mask = (const int*)d_in[1];
    const float* q_w  = (const float*)d_in[2];
    const float* q_b  = (const float*)d_in[3];
    const float* k_w  = (const float*)d_in[4];
    const float* k_b  = (const float*)d_in[5];
    const float* v_w  = (const float*)d_in[6];
    const float* v_b  = (const float*)d_in[7];
    const float* o_w  = (const float*)d_in[8];
    const float* o_b  = (const float*)d_in[9];
    float* out = (float*)d_out;

    const size_t SEG = (size_t)MTOK * DIM;        // 4M elements (8 MB bf16)
    ushort* Qbf = (ushort*)d_out;                 // d_out[0:8MB]
    ushort* Xbf = Qbf + SEG;                      // d_out[8:16MB]
    ushort* Kb  = (ushort*)d_ws;                  // ws[0:8MB]
    ushort* Cb  = Kb + SEG;                       // ws[8:16MB]
    ushort* Vt  = Cb + SEG;                       // ws[16:24MB]
    ushort* Wbf = Vt + SEG;                       // ws[24:32MB]

    const bool big = ws_size >= (size_t)32 * 1024 * 1024;

    if (big) {
        conv_all<<<8192, 256, 0, stream>>>(x, q_w, k_w, v_w, o_w, Xbf, Wbf);
        gemm_qkv<<<(MTOK / 128) * (3072 / 128), 256, 0, stream>>>(
            Xbf, Wbf, q_b, k_b, v_b, Qbf, Kb, Vt);
        flash_attn<<<dim3(QLEN / 128, BS * NH), 256, 0, stream>>>(Qbf, Kb, Vt, mask, Cb);
        gemm_o<<<(MTOK / 128) * (DIM / 64), 256, 0, stream>>>(
            Cb, Wbf + 3 * (size_t)(DIM * DIM), o_b, out);
    } else {
        const int tiles   = (MTOK / 16) * (DIM / 16);
        const int gblocks = tiles / 4;
        gemm_f32in_bf16out<<<gblocks, 256, 0, stream>>>(x, q_w, q_b, Qbf, MTOK, DIM, DIM, QSCALE);
        gemm_f32in_bf16out<<<gblocks, 256, 0, stream>>>(x, k_w, k_b, Kb,  MTOK, DIM, DIM, 1.0f);
        gemm_f32in_bf16out<<<gblocks, 256, 0, stream>>>(x, v_w, v_b, Cb,  MTOK, DIM, DIM, 1.0f);
        transpose_v<<<dim3(QLEN / 64, BS * NH), 256, 0, stream>>>(Cb, Vt);
        flash_attn<<<dim3(QLEN / 128, BS * NH), 256, 0, stream>>>(Qbf, Kb, Vt, mask, Cb);
        gemm_bf16in_f32out<<<tiles / 4, 256, 0, stream>>>(Cb, o_w, o_b, out, MTOK, DIM, DIM);
    }
}